// Round 7
// baseline (320.011 us; speedup 1.0000x reference)
//
#include <hip/hip_runtime.h>

// Problem constants (fixed by the harness / reference setup_inputs)
#define B_ 2
#define K_ 33
#define N_ 50000
#define E_ 800000
#define R_ 200
#define D_ 64
#define L_ 3

#define ROWCAP 95000      // rowlist entries (tail carved for tree-barrier state)
#define NV4 200000        // E/4 int4-groups
#define SCAT_BLOCKS 391   // fallback scan grid
#define SCAT_THREADS (SCAT_BLOCKS * 256)
#define FGRID 256         // fused grid: 1 block/CU, co-resident via cooperative launch
#define FTHREADS (FGRID * 256)
#define NGRP 16           // barrier tree: 16 groups x 16 blocks
#define GSZ  16
#define READY_MAGIC 0x5F0F00D5CAFEB007ull

#define SCOPE_AG __HIP_MEMORY_SCOPE_AGENT

// ---- relaxed agent-scope (cross-XCD coherent, no cache-wide fences) ----
// R4-R6 lessons: ockl grid.sync ~45us/barrier (flush+contention); flat
// fence-free barrier ~6us; tree barrier ~3us. Remaining cost is the
// agent-scope BODY: ~8.4M uncached memory-side ops ran at ~22 ops/cy
// (~190us). This round cuts op count ~4x (lazy agg init, LDS-built
// frontier bitset, u64 widening).
__device__ inline float aldf(float* p)            { return __hip_atomic_load(p, __ATOMIC_RELAXED, SCOPE_AG); }
__device__ inline void  astf(float* p, float v)   { __hip_atomic_store(p, v, __ATOMIC_RELAXED, SCOPE_AG); }
__device__ inline int   aldi(int* p)              { return __hip_atomic_load(p, __ATOMIC_RELAXED, SCOPE_AG); }
__device__ inline void  asti(int* p, int v)       { __hip_atomic_store(p, v, __ATOMIC_RELAXED, SCOPE_AG); }
__device__ inline unsigned aldu(unsigned* p)      { return __hip_atomic_load(p, __ATOMIC_RELAXED, SCOPE_AG); }
__device__ inline void  astu(unsigned* p, unsigned v) { __hip_atomic_store(p, v, __ATOMIC_RELAXED, SCOPE_AG); }
__device__ inline unsigned long long ald64(unsigned long long* p) { return __hip_atomic_load(p, __ATOMIC_RELAXED, SCOPE_AG); }
__device__ inline void  ast64(unsigned long long* p, unsigned long long v) { __hip_atomic_store(p, v, __ATOMIC_RELAXED, SCOPE_AG); }

// Two-level tree barrier, monotonic epochs (no reset races). See R6.
__device__ inline void gridbar(unsigned* bar, unsigned epoch) {
    __syncthreads();    // per-wave vmcnt(0) drain before s_barrier = release
    if (threadIdx.x == 0) {
        const int g = (int)(blockIdx.x >> 4);
        unsigned* gcnt = bar + (1 + g) * 32;
        unsigned* ggo  = gcnt + 1;
        unsigned prev = __hip_atomic_fetch_add(gcnt, 1u, __ATOMIC_RELAXED, SCOPE_AG);
        if (prev == epoch * GSZ - 1) {              // last arriver in group
            unsigned r = __hip_atomic_fetch_add(bar, 1u, __ATOMIC_RELAXED, SCOPE_AG);
            if (r == epoch * NGRP - 1) {            // last group -> release everyone
                #pragma unroll
                for (int i = 0; i < NGRP; ++i)
                    astu(bar + (1 + i) * 32 + 1, epoch);
            }
        }
        while (aldu(ggo) < epoch) __builtin_amdgcn_s_sleep(1);
    }
    __syncthreads();
}

__device__ inline float wave_sum64(float v) {
    for (int m = 32; m; m >>= 1) v += __shfl_xor(v, m, 64);
    return v;
}

// flags bits: 1 = x-active; 4 = in rowlist (claimed ever);
//             8 = agg init CLAIMED this layer; 16 = agg init DONE this layer.
// Invariant: bit8 set => bit4 set. Update clears 8|16 (agg becomes stale;
// next layer's first toucher re-zeroes the row).
//
// Workspace layout (proven ws_size >= 52,000,288):
//   x       @ 0           25,600,000  (reads gated by flags bit0)
//   agg     @ 25,600,000  25,600,000  (lazy-zeroed per touched row)
//   flags   @ 51,200,000     400,000  (zeroed by block 0 in P0)
//   rowlist @ 51,600,000     380,000  (ROWCAP entries)
//   bar     @ 51,980,032       2,176  (17 x 128 B tree-barrier lines)
//   ready   @ 51,987,480  (u64 magic)
//   rowcnt  @ 52,000,000  frontcnt @ +4  hb @ +8  rb @ +16  tb @ +24

struct FusedArgs {
    const float *rel, *layer_w, *layer_b, *ln_g, *ln_b;
    const float *mlp_w1, *mlp_b1, *mlp_w2, *mlp_b2;
    const int *raw, *ei, *etype;
    char* ws;
    float* out;
};

__global__ __launch_bounds__(256) void fused_kernel(FusedArgs A) {
    char* ws = A.ws;
    float*    x       = (float*)(ws);
    float*    agg     = (float*)(ws + 25600000);
    int*      flags   = (int*)(ws + 51200000);
    int*      rowlist = (int*)(ws + 51600000);
    unsigned* bar     = (unsigned*)(ws + 51980032);
    unsigned long long* ready = (unsigned long long*)(ws + 51987480);
    int*      rowcnt  = (int*)(ws + 52000000);
    int*      frontcnt= (int*)(ws + 52000004);
    int*      hb      = (int*)(ws + 52000008);
    int*      rb      = (int*)(ws + 52000016);
    int*      tb      = (int*)(ws + 52000024);
    unsigned long long* xu   = (unsigned long long*)x;    // row*32 + lane
    unsigned long long* aggu = (unsigned long long*)agg;

    const int tid  = threadIdx.x;
    const int lane = tid & 63;
    const int gtid = blockIdx.x * 256 + tid;
    const int gw   = gtid >> 6;                 // global wave id, 0..1023

    __shared__ unsigned long long bsll[1564];   // 12,512 B LDS frontier bitset
    __shared__ int nz_s, cnt_s, fc_s;

    // ---- barrier bootstrap over poisoned ws (block0 publishes magic) ----
    if (blockIdx.x == 0) {
        for (int i = tid; i < 17 * 32; i += 256) astu(&bar[i], 0u);
        __syncthreads();                        // drains all zero-stores
        if (tid == 0) ast64(ready, READY_MAGIC);
    } else if (tid == 0) {
        while (ald64(ready) != READY_MAGIC) __builtin_amdgcn_s_sleep(1);
    }

    // ---------- P0 (block 0 only): zero flags + decode + seed ----------
    if (blockIdx.x == 0) {
        unsigned long long* fz = (unsigned long long*)flags;  // 50,000 u64
        for (int i = tid; i < 50000; i += 256) ast64(&fz[i], 0ull);
        if (tid == 0) { asti(rowcnt, 0); asti(frontcnt, B_); nz_s = 0; }
        __syncthreads();        // flags-zero drained before seeds below
        // int64-vs-int32 batch detect: any hi-word nonzero -> int32 (stride 1)
        if (tid < 99 && A.raw[2 * tid + 1] != 0) atomicOr(&nz_s, 1);
        __syncthreads();
        const int st = nz_s ? 1 : 2;
        for (int i = tid; i < B_ * K_; i += 256) asti(&tb[i], A.raw[(i * 3 + 1) * st]);
        if (tid < B_) {
            asti(&hb[tid], A.raw[(tid * K_ * 3 + 0) * st]);
            asti(&rb[tid], A.raw[(tid * K_ * 3 + 2) * st]);
        }
        __syncthreads();
        if (tid < 128) {
            int b = tid >> 6;
            int h = A.raw[(b * K_ * 3 + 0) * st];
            int r = A.raw[(b * K_ * 3 + 2) * st];
            int row = b * N_ + h;
            astf(&x[row * D_ + lane], A.rel[(b * R_ + r) * D_ + lane]);
            if (lane == 0) {
                asti(&flags[row], 1 | 4);       // x-active, claimed; NOT agg-init
                int idx = atomicAdd(rowcnt, 1);
                asti(&rowlist[idx], row);
            }
        }
    }
    unsigned bark = 0;
    gridbar(bar, ++bark);

    // hb/rb constant after P0 — hoist coherent reads once.
    const int hb0 = aldi(&hb[0]), hb1 = aldi(&hb[1]);
    const int rb0 = aldi(&rb[0]), rb1 = aldi(&rb[1]);

    // ---------- layers ----------
    for (int l = 0; l < L_; ++l) {
        const float* W    = A.layer_w + (size_t)l * 128 * 64;
        const float* bias = A.layer_b + l * 64;
        const float* gam  = A.ln_g + l * 64;
        const float* bet  = A.ln_b + l * 64;

        // ---- build LDS bitset from the frontier list (rowlist[0..frontcnt)) ----
        for (int i = tid; i < 1564; i += 256) bsll[i] = 0ull;
        if (tid == 0) fc_s = min(aldi(frontcnt), ROWCAP);
        __syncthreads();
        {
            unsigned* bsw = (unsigned*)bsll;
            for (int i = tid; i < fc_s; i += 256) {
                int row = aldi(&rowlist[i]);
                int b = (row >= N_) ? 1 : 0;
                int node = row - b * N_;
                atomicOr(&bsw[node >> 4], 1u << (((node & 15) << 1) | b));
            }
        }
        __syncthreads();

        // ---- scan: O(E) cached probe + ballot-compacted active-edge scatter ----
        {
            const unsigned* bs = (const unsigned*)bsll;
            // NV4 % 64 == 0 and stride % 64 == 0 -> trip count wave-uniform.
            for (int i = gtid; i < NV4; i += FTHREADS) {
                int4 u = ((const int4*)A.ei)[i];        // ei read-only: plain cached
                int sv[4] = {u.x, u.y, u.z, u.w};
                unsigned act = 0;
                #pragma unroll
                for (int k = 0; k < 4; ++k) {
                    int s = sv[k];
                    act |= ((bs[s >> 4] >> ((s & 15) << 1)) & 3u) << (k * 2);
                }
                int ibase = i - lane;                   // wave-uniform int4 base
                #pragma unroll
                for (int k = 0; k < 4; ++k) {
                    #pragma unroll
                    for (int b = 0; b < B_; ++b) {
                        unsigned long long mask = __ballot((act >> (k * 2 + b)) & 1);
                        while (mask) {
                            int j = __builtin_ctzll(mask);
                            mask &= mask - 1;
                            int e  = (ibase + j) * 4 + k;
                            int si = __shfl(sv[k], j, 64);
                            int di = A.ei[E_ + e];      // lane-uniform, read-only
                            int ti = A.etype[e];
                            int drow = b * N_ + di;
                            // lazy agg init: claim bit8; initializer zeroes row.
                            int oldv = 0;
                            if (lane == 0) oldv = atomicOr(&flags[drow], 8 | 4);
                            oldv = __shfl(oldv, 0, 64);
                            if (!(oldv & 8)) {          // this wave initializes
                                if (lane < 32) ast64(&aggu[drow * 32 + lane], 0ull);
                                asm volatile("s_waitcnt vmcnt(0)" ::: "memory");
                                if (lane == 0) {
                                    atomicOr(&flags[drow], 16);     // publish
                                    if (!(oldv & 4)) {              // first-ever claim
                                        int idx = atomicAdd(rowcnt, 1);
                                        if (idx < ROWCAP) asti(&rowlist[idx], drow);
                                    }
                                }
                            } else if (!(oldv & 16)) {  // init in flight elsewhere
                                if (lane == 0)
                                    while (!(aldi(&flags[drow]) & 16))
                                        __builtin_amdgcn_s_sleep(1);
                            }
                            // v = x[src] * rel[type]; u64-wide x load + shfl unpack
                            float xlo_ = 0.f, xhi_ = 0.f;
                            int srow = b * N_ + si;
                            if (lane < 32) {
                                unsigned long long xv = ald64(&xu[srow * 32 + lane]);
                                xlo_ = __uint_as_float((unsigned)xv);
                                xhi_ = __uint_as_float((unsigned)(xv >> 32));
                            }
                            float xlo = __shfl(xlo_, lane >> 1, 64);
                            float xhi = __shfl(xhi_, lane >> 1, 64);
                            float v = ((lane & 1) ? xhi : xlo)
                                    * A.rel[(b * R_ + ti) * D_ + lane];
                            atomicAdd(&agg[drow * D_ + lane], v);
                        }
                    }
                }
            }
        }
        gridbar(bar, ++bark);

        // ---- update: [agg(+boundary), x] @ W + b -> LN -> relu -> x += ----
        {
            if (tid == 0) cnt_s = min(aldi(rowcnt), ROWCAP);
            __syncthreads();
            const int cnt = cnt_s;
            if (blockIdx.x == 0 && tid == 0) asti(frontcnt, cnt);  // next frontier
            for (int idx = gw; idx < cnt; idx += FTHREADS >> 6) {
                int row = aldi(&rowlist[idx]);
                int f = aldi(&flags[row]);
                int b = (row >= N_) ? 1 : 0;
                int node = row - b * N_;
                float a = 0.f;
                if (f & 8) {                    // touched this layer: agg valid
                    float alo_ = 0.f, ahi_ = 0.f;
                    if (lane < 32) {
                        unsigned long long av = ald64(&aggu[row * 32 + lane]);
                        alo_ = __uint_as_float((unsigned)av);
                        ahi_ = __uint_as_float((unsigned)(av >> 32));
                    }
                    float alo = __shfl(alo_, lane >> 1, 64);
                    float ahi = __shfl(ahi_, lane >> 1, 64);
                    a = (lane & 1) ? ahi : alo;
                }
                if (node == (b ? hb1 : hb0))    // boundary (= query)
                    a += A.rel[(b * R_ + (b ? rb1 : rb0)) * D_ + lane];
                float xo = 0.f;
                if (f & 1) {
                    float xlo_ = 0.f, xhi_ = 0.f;
                    if (lane < 32) {
                        unsigned long long xv = ald64(&xu[row * 32 + lane]);
                        xlo_ = __uint_as_float((unsigned)xv);
                        xhi_ = __uint_as_float((unsigned)(xv >> 32));
                    }
                    float xlo = __shfl(xlo_, lane >> 1, 64);
                    float xhi = __shfl(xhi_, lane >> 1, 64);
                    xo = (lane & 1) ? xhi : xlo;
                }
                float y = bias[lane];
                #pragma unroll 8
                for (int i = 0; i < 64; ++i)
                    y += __shfl(a, i, 64) * W[i * 64 + lane];
                #pragma unroll 8
                for (int i = 0; i < 64; ++i)
                    y += __shfl(xo, i, 64) * W[(64 + i) * 64 + lane];
                float mu = wave_sum64(y) * (1.0f / 64.0f);
                float dlt = y - mu;
                float var = wave_sum64(dlt * dlt) * (1.0f / 64.0f);
                float upd = fmaxf(dlt * rsqrtf(var + 1e-5f) * gam[lane] + bet[lane], 0.0f);
                float res = upd + xo;
                float slo = __shfl(res, 2 * lane, 64);
                float shi = __shfl(res, 2 * lane + 1, 64);
                if (lane < 32) {
                    unsigned long long pv = ((unsigned long long)__float_as_uint(shi) << 32)
                                          | (unsigned long long)__float_as_uint(slo);
                    ast64(&xu[row * 32 + lane], pv);
                }
                if (lane == 0)
                    asti(&flags[row], (f | 1) & ~(8 | 16));   // x-active; agg stale
            }
        }
        gridbar(bar, ++bark);
    }

    // ---------- score ----------
    if (gw < B_ * K_) {
        int b = gw / K_;
        int t = aldi(&tb[gw]);
        int row = b * N_ + t;
        float q   = A.rel[(b * R_ + (b ? rb1 : rb0)) * D_ + lane];
        float hid = (aldi(&flags[row]) & 1) ? aldf(&x[row * D_ + lane]) : 0.0f;
        float acc = A.mlp_b1[lane];
        #pragma unroll 8
        for (int i = 0; i < 64; ++i) acc += __shfl(hid, i, 64) * A.mlp_w1[i * 64 + lane];
        #pragma unroll 8
        for (int i = 0; i < 64; ++i) acc += __shfl(q, i, 64) * A.mlp_w1[(64 + i) * 64 + lane];
        acc = fmaxf(acc, 0.0f);
        float s = wave_sum64(acc * A.mlp_w2[lane]);
        if (lane == 0) A.out[gw] = s + A.mlp_b2[0];
    }

    // Reset magic so a future run never sees stale MAGIC with un-zeroed
    // counters (hang hazard if a poison pass is ever skipped).
    if (blockIdx.x == 0 && tid == 0) ast64(ready, 0ull);
}

// =====================================================================
// Fallback path: proven R1 multi-kernel pipeline (launch-error only)
// =====================================================================
__global__ void init_kernel(const int* __restrict__ raw,
                            int* __restrict__ hb, int* __restrict__ rb,
                            int* __restrict__ tb,
                            float* __restrict__ x, int* __restrict__ flags,
                            unsigned* __restrict__ bitset,
                            int* __restrict__ rowlist, int* __restrict__ rowcnt,
                            const float* __restrict__ rel) {
    __shared__ int stride_s;
    __shared__ int hs[B_], rs[B_];
    if (threadIdx.x == 0) {
        int all_hi_zero = 1;
        for (int i = 0; i < 99; i++)
            if (raw[2 * i + 1] != 0) { all_hi_zero = 0; break; }
        stride_s = all_hi_zero ? 2 : 1;
    }
    __syncthreads();
    int st = stride_s;
    for (int i = threadIdx.x; i < B_ * K_; i += blockDim.x)
        tb[i] = raw[(i * 3 + 1) * st];
    if (threadIdx.x < B_) {
        int b = threadIdx.x;
        int h = raw[(b * K_ * 3 + 0) * st];
        int r = raw[(b * K_ * 3 + 2) * st];
        hb[b] = h; rb[b] = r; hs[b] = h; rs[b] = r;
    }
    __syncthreads();
    int b = threadIdx.x >> 6;
    int lane = threadIdx.x & 63;
    int node = hs[b];
    int row = b * N_ + node;
    x[row * D_ + lane] = rel[(b * R_ + rs[b]) * D_ + lane];
    if (lane == 0) {
        atomicOr(&flags[row], 1 | 4);
        atomicOr(&bitset[node >> 4], 1u << (((node & 15) << 1) | b));
        int idx = atomicAdd(rowcnt, 1);
        if (idx < ROWCAP) rowlist[idx] = row;
    }
}

__global__ void scatter_kernel(const float* __restrict__ x, float* __restrict__ agg,
                               const int* __restrict__ ei, const int* __restrict__ etype,
                               const float* __restrict__ rel,
                               int* __restrict__ flags,
                               const unsigned* __restrict__ bitset,
                               int* __restrict__ rowlist, int* __restrict__ rowcnt) {
    __shared__ uint4 bs4[782];
    unsigned* bs = (unsigned*)bs4;
    const uint4* g4 = (const uint4*)bitset;
    for (int i = threadIdx.x; i < 781; i += 256) bs4[i] = g4[i];
    if (threadIdx.x == 0) bs[3124] = bitset[3124];
    const int t = blockIdx.x * 256 + threadIdx.x;
    const int4* s4 = (const int4*)ei;
    int4 u0 = s4[t];
    int v4p1 = t + SCAT_THREADS;
    bool ok1 = v4p1 < NV4;
    int4 u1 = s4[ok1 ? v4p1 : t];
    __syncthreads();
    const int lane = threadIdx.x & 63;
    const int wv4 = blockIdx.x * 256 + (threadIdx.x & ~63);
    #pragma unroll
    for (int p = 0; p < 2; p++) {
        int4 u = p ? u1 : u0;
        bool ok = p ? ok1 : true;
        int sv[4] = {u.x, u.y, u.z, u.w};
        unsigned act = 0;
        if (ok) {
            #pragma unroll
            for (int k = 0; k < 4; k++) {
                int s = sv[k];
                act |= ((bs[s >> 4] >> ((s & 15) << 1)) & 3u) << (k * 2);
            }
        }
        #pragma unroll
        for (int k = 0; k < 4; k++) {
            #pragma unroll
            for (int b = 0; b < B_; b++) {
                unsigned long long mask = __ballot((act >> (k * 2 + b)) & 1);
                while (mask) {
                    int i = __builtin_ctzll(mask);
                    mask &= mask - 1;
                    int e = (wv4 + i + p * SCAT_THREADS) * 4 + k;
                    int si = __shfl(sv[k], i, 64);
                    int di = ei[E_ + e];
                    int ti = etype[e];
                    float v = x[(b * N_ + si) * D_ + lane] * rel[(b * R_ + ti) * D_ + lane];
                    atomicAdd(&agg[(b * N_ + di) * D_ + lane], v);
                    if (lane == 0) {
                        int old = atomicOr(&flags[b * N_ + di], 2 | 4);
                        if (!(old & 4)) {
                            int idx = atomicAdd(rowcnt, 1);
                            if (idx < ROWCAP) rowlist[idx] = b * N_ + di;
                        }
                    }
                }
            }
        }
    }
}

__global__ void update_kernel(float* __restrict__ x, float* __restrict__ agg,
                              int* __restrict__ flags, unsigned* __restrict__ bitset,
                              const int* __restrict__ rowlist,
                              const int* __restrict__ rowcnt,
                              const int* __restrict__ hb, const int* __restrict__ rb,
                              const float* __restrict__ rel,
                              const float* __restrict__ W,
                              const float* __restrict__ bias,
                              const float* __restrict__ g,
                              const float* __restrict__ be) {
    const int lane = threadIdx.x & 63;
    const int cnt = min(*rowcnt, ROWCAP);
    int idx = blockIdx.x * (blockDim.x >> 6) + (threadIdx.x >> 6);
    const int nw = gridDim.x * (blockDim.x >> 6);
    for (; idx < cnt; idx += nw) {
        int row = rowlist[idx];
        int f = flags[row];
        int b = (row >= N_) ? 1 : 0;
        int node = row - b * N_;
        float a = agg[row * D_ + lane];
        if (row == b * N_ + hb[b])
            a += rel[(b * R_ + rb[b]) * D_ + lane];
        float xo = (f & 1) ? x[row * D_ + lane] : 0.0f;
        float y = bias[lane];
        #pragma unroll 8
        for (int i = 0; i < 64; i++) {
            float av = __shfl(a, i, 64);
            y += av * W[i * 64 + lane];
        }
        #pragma unroll 8
        for (int i = 0; i < 64; i++) {
            float xv = __shfl(xo, i, 64);
            y += xv * W[(64 + i) * 64 + lane];
        }
        float mu = wave_sum64(y) * (1.0f / 64.0f);
        float dlt = y - mu;
        float var = wave_sum64(dlt * dlt) * (1.0f / 64.0f);
        float upd = dlt * rsqrtf(var + 1e-5f) * g[lane] + be[lane];
        upd = fmaxf(upd, 0.0f);
        x[row * D_ + lane] = upd + xo;
        agg[row * D_ + lane] = 0.0f;
        if (lane == 0) {
            flags[row] = (f | 1) & ~2;
            atomicOr(&bitset[node >> 4], 1u << (((node & 15) << 1) | b));
        }
    }
}

__global__ void score_kernel(const float* __restrict__ x, const int* __restrict__ flags,
                             const int* __restrict__ tb, const int* __restrict__ rb,
                             const float* __restrict__ rel,
                             const float* __restrict__ w1,
                             const float* __restrict__ b1,
                             const float* __restrict__ w2,
                             const float* __restrict__ b2,
                             float* __restrict__ out) {
    int idx = blockIdx.x;
    int lane = threadIdx.x;
    int b = idx / K_;
    int t  = tb[idx];
    int r0 = rb[b];
    int row = b * N_ + t;
    float q   = rel[(b * R_ + r0) * D_ + lane];
    float hid = (flags[row] & 1) ? x[row * D_ + lane] : 0.0f;
    float acc = b1[lane];
    #pragma unroll 8
    for (int i = 0; i < 64; i++) acc += __shfl(hid, i, 64) * w1[i * 64 + lane];
    #pragma unroll 8
    for (int i = 0; i < 64; i++) acc += __shfl(q, i, 64) * w1[(64 + i) * 64 + lane];
    acc = fmaxf(acc, 0.0f);
    float s = wave_sum64(acc * w2[lane]);
    if (lane == 0) out[idx] = s + b2[0];
}

extern "C" void kernel_launch(void* const* d_in, const int* in_sizes, int n_in,
                              void* d_out, int out_size, void* d_ws, size_t ws_size,
                              hipStream_t stream) {
    const float* rel     = (const float*)d_in[0];
    const float* layer_w = (const float*)d_in[1];
    const float* layer_b = (const float*)d_in[2];
    const float* ln_g    = (const float*)d_in[3];
    const float* ln_b    = (const float*)d_in[4];
    const float* mlp_w1  = (const float*)d_in[5];
    const float* mlp_b1  = (const float*)d_in[6];
    const float* mlp_w2  = (const float*)d_in[7];
    const float* mlp_b2  = (const float*)d_in[8];
    const int* batch_raw = (const int*)d_in[9];
    const int* ei    = (const int*)d_in[10];
    const int* etype = (const int*)d_in[11];
    (void)in_sizes; (void)n_in; (void)out_size; (void)ws_size;

    char* ws = (char*)d_ws;

    FusedArgs fa;
    fa.rel = rel; fa.layer_w = layer_w; fa.layer_b = layer_b;
    fa.ln_g = ln_g; fa.ln_b = ln_b;
    fa.mlp_w1 = mlp_w1; fa.mlp_b1 = mlp_b1; fa.mlp_w2 = mlp_w2; fa.mlp_b2 = mlp_b2;
    fa.raw = batch_raw; fa.ei = ei; fa.etype = etype;
    fa.ws = ws; fa.out = (float*)d_out;
    void* kargs[] = { (void*)&fa };

    hipError_t err = hipLaunchCooperativeKernel(fused_kernel, dim3(FGRID), dim3(256),
                                                kargs, 0, stream);
    if (err != hipSuccess) {
        (void)hipGetLastError();                // clear sticky error
        // ---------- Fallback: proven R1 multi-kernel path ----------
        float* x        = (float*)(ws);
        float* agg      = (float*)(ws + 25600000);
        int* flags      = (int*)  (ws + 51200000);
        int* rowlist    = (int*)  (ws + 51600000);
        unsigned* bitset= (unsigned*)(ws + 51987488);
        int* rowcnt     = (int*)  (ws + 52000000);
        int* hb         = (int*)  (ws + 52000008);
        int* rb         = (int*)  (ws + 52000016);
        int* tb         = (int*)  (ws + 52000024);

        hipMemsetAsync(ws + 25600000, 0, 26400288, stream);
        init_kernel<<<1, 128, 0, stream>>>(batch_raw, hb, rb, tb, x, flags, bitset,
                                           rowlist, rowcnt, rel);
        for (int l = 0; l < L_; l++) {
            scatter_kernel<<<SCAT_BLOCKS, 256, 0, stream>>>(x, agg, ei, etype, rel,
                                                            flags, bitset, rowlist, rowcnt);
            update_kernel<<<256, 256, 0, stream>>>(x, agg, flags, bitset,
                                                   rowlist, rowcnt, hb, rb, rel,
                                                   layer_w + (size_t)l * 128 * 64,
                                                   layer_b + l * 64,
                                                   ln_g + l * 64,
                                                   ln_b + l * 64);
        }
        score_kernel<<<B_ * K_, 64, 0, stream>>>(x, flags, tb, rb, rel, mlp_w1, mlp_b1,
                                                 mlp_w2, mlp_b2, (float*)d_out);
    }
}

// Round 8
// 182.046 us; speedup vs baseline: 1.7579x; 1.7579x over previous
//
#include <hip/hip_runtime.h>

// Problem constants (fixed by the harness / reference setup_inputs)
#define B_ 2
#define K_ 33
#define N_ 50000
#define E_ 800000
#define R_ 200
#define D_ 64
#define L_ 3

#define ROWCAP 95000      // rowlist entries (tail carved for tree-barrier state)
#define NV4 200000        // E/4 int4-groups
#define SCAT_BLOCKS 391   // fallback scan grid
#define SCAT_THREADS (SCAT_BLOCKS * 256)
#define FGRID 256         // fused grid: 1 block/CU, co-resident via cooperative launch
#define FTHREADS (FGRID * 256)
#define NGRP 16           // barrier tree: 16 groups x 16 blocks
#define GSZ  16
#define READY_MAGIC 0x5F0F00D5CAFEB007ull

#define SCOPE_AG __HIP_MEMORY_SCOPE_AGENT

// ---- relaxed agent-scope (cross-XCD coherent, no cache-wide fences) ----
// R4-R7 lessons: ockl grid.sync ~45us/barrier; flat fence-free ~6us; tree
// ~3us. Body cost = SERIALIZED coherence round trips per wave (R6 vs R7
// A/B: op count dropped 4x, time unchanged; R7's per-edge dependent
// atomicOr-return + vmcnt(0) chains made it slightly WORSE). This round
// removes the two biggest round-trip populations algorithmically:
// L3 scatter claims (~9300) and L3 update rows (~9500 -> 66 targets).
__device__ inline float aldf(float* p)            { return __hip_atomic_load(p, __ATOMIC_RELAXED, SCOPE_AG); }
__device__ inline void  astf(float* p, float v)   { __hip_atomic_store(p, v, __ATOMIC_RELAXED, SCOPE_AG); }
__device__ inline int   aldi(int* p)              { return __hip_atomic_load(p, __ATOMIC_RELAXED, SCOPE_AG); }
__device__ inline void  asti(int* p, int v)       { __hip_atomic_store(p, v, __ATOMIC_RELAXED, SCOPE_AG); }
__device__ inline unsigned aldu(unsigned* p)      { return __hip_atomic_load(p, __ATOMIC_RELAXED, SCOPE_AG); }
__device__ inline void  astu(unsigned* p, unsigned v) { __hip_atomic_store(p, v, __ATOMIC_RELAXED, SCOPE_AG); }
__device__ inline unsigned long long ald64(unsigned long long* p) { return __hip_atomic_load(p, __ATOMIC_RELAXED, SCOPE_AG); }
__device__ inline void  ast64(unsigned long long* p, unsigned long long v) { __hip_atomic_store(p, v, __ATOMIC_RELAXED, SCOPE_AG); }

// Two-level tree barrier, monotonic epochs (no reset races). See R6.
__device__ inline void gridbar(unsigned* bar, unsigned epoch) {
    __syncthreads();    // per-wave vmcnt(0) drain before s_barrier = release
    if (threadIdx.x == 0) {
        const int g = (int)(blockIdx.x >> 4);
        unsigned* gcnt = bar + (1 + g) * 32;
        unsigned* ggo  = gcnt + 1;
        unsigned prev = __hip_atomic_fetch_add(gcnt, 1u, __ATOMIC_RELAXED, SCOPE_AG);
        if (prev == epoch * GSZ - 1) {              // last arriver in group
            unsigned r = __hip_atomic_fetch_add(bar, 1u, __ATOMIC_RELAXED, SCOPE_AG);
            if (r == epoch * NGRP - 1) {            // last group -> release everyone
                #pragma unroll
                for (int i = 0; i < NGRP; ++i)
                    astu(bar + (1 + i) * 32 + 1, epoch);
            }
        }
        while (aldu(ggo) < epoch) __builtin_amdgcn_s_sleep(1);
    }
    __syncthreads();
}

__device__ inline float wave_sum64(float v) {
    for (int m = 32; m; m >>= 1) v += __shfl_xor(v, m, 64);
    return v;
}

// flags bits: 1 = x-active, 4 = rowlist claim.
// Workspace layout (proven ws_size >= 52,000,288):
//   x       @ 0           25,600,000  (reads gated by flags bit0)
//   agg     @ 25,600,000  25,600,000  (eager-zeroed in P0; update re-zeroes)
//   flags   @ 51,200,000     400,000  (zeroed in P0)
//   rowlist @ 51,600,000     380,000  (ROWCAP entries)
//   bar     @ 51,980,032       2,176  (17 x 128 B tree-barrier lines)
//   ready   @ 51,987,480  (u64 magic)
//   bitset  @ 51,987,488      12,512  (dual-bit src-activity; 1564 u64)
//   rowcnt  @ 52,000,000  hb @ +8  rb @ +16  tb @ +24 (264 B)

struct FusedArgs {
    const float *rel, *layer_w, *layer_b, *ln_g, *ln_b;
    const float *mlp_w1, *mlp_b1, *mlp_w2, *mlp_b2;
    const int *raw, *ei, *etype;
    char* ws;
    float* out;
};

__global__ __launch_bounds__(256) void fused_kernel(FusedArgs A) {
    char* ws = A.ws;
    float*    x       = (float*)(ws);
    float*    agg     = (float*)(ws + 25600000);
    int*      flags   = (int*)(ws + 51200000);
    int*      rowlist = (int*)(ws + 51600000);
    unsigned* bar     = (unsigned*)(ws + 51980032);
    unsigned long long* ready = (unsigned long long*)(ws + 51987480);
    unsigned* bitset  = (unsigned*)(ws + 51987488);
    int*      rowcnt  = (int*)(ws + 52000000);
    int*      hb      = (int*)(ws + 52000008);
    int*      rb      = (int*)(ws + 52000016);
    int*      tb      = (int*)(ws + 52000024);
    unsigned long long* gbs = (unsigned long long*)bitset;   // 1564 u64

    const int tid  = threadIdx.x;
    const int lane = tid & 63;
    const int gtid = blockIdx.x * 256 + tid;
    const int gw   = gtid >> 6;                 // global wave id, 0..1023

    __shared__ unsigned long long bsll[1564];   // 12,512 B staged src-activity bitset
    __shared__ unsigned long long tact[1564];   // 12,512 B target-dst bitset (L3 filter)
    __shared__ int tbl_s[B_ * K_];              // staged t-indices (66)
    __shared__ int nz_s, cnt_s;

    // ---- barrier bootstrap over poisoned ws (block0 publishes magic) ----
    if (blockIdx.x == 0) {
        for (int i = tid; i < 17 * 32; i += 256) astu(&bar[i], 0u);
        __syncthreads();                        // drains all zero-stores
        if (tid == 0) ast64(ready, READY_MAGIC);
    } else if (tid == 0) {
        while (ald64(ready) != READY_MAGIC) __builtin_amdgcn_s_sleep(1);
    }

    // ---------- P0: zero + decode + seed ----------
    // Block 0: flags + bitset + counters + batch decode + seed rows.
    // Blocks 1..255: eager agg zero (R6 form; measured faster than lazy).
    if (blockIdx.x == 0) {
        unsigned long long* fz = (unsigned long long*)flags;  // 50,000 u64
        for (int i = tid; i < 50000; i += 256) ast64(&fz[i], 0ull);
        for (int i = tid; i < 1564; i += 256) ast64(&gbs[i], 0ull);
        if (tid == 0) { asti(rowcnt, 0); nz_s = 0; }
        __syncthreads();
        // int64-vs-int32 batch detect: any hi-word nonzero -> int32 (stride 1)
        if (tid < 99 && A.raw[2 * tid + 1] != 0) atomicOr(&nz_s, 1);
        __syncthreads();
        const int st = nz_s ? 1 : 2;
        for (int i = tid; i < B_ * K_; i += 256) asti(&tb[i], A.raw[(i * 3 + 1) * st]);
        if (tid < B_) {
            asti(&hb[tid], A.raw[(tid * K_ * 3 + 0) * st]);
            asti(&rb[tid], A.raw[(tid * K_ * 3 + 2) * st]);
        }
        __syncthreads();
        if (tid < 128) {
            int b = tid >> 6;
            int h = A.raw[(b * K_ * 3 + 0) * st];
            int r = A.raw[(b * K_ * 3 + 2) * st];
            int row = b * N_ + h;
            astf(&x[row * D_ + lane], A.rel[(b * R_ + r) * D_ + lane]);
            if (lane == 0) {
                asti(&flags[row], 1 | 4);
                atomicOr(&bitset[h >> 4], 1u << (((h & 15) << 1) | b));
                int idx = atomicAdd(rowcnt, 1);
                asti(&rowlist[idx], row);
            }
        }
    } else {
        unsigned long long* az = (unsigned long long*)agg;    // 3,200,000 u64
        for (int i = (blockIdx.x - 1) * 256 + tid; i < 3200000; i += 255 * 256)
            ast64(&az[i], 0ull);
    }
    unsigned bark = 0;
    gridbar(bar, ++bark);

    // hb/rb constant after P0 — hoist coherent reads once.
    const int hb0 = aldi(&hb[0]), hb1 = aldi(&hb[1]);
    const int rb0 = aldi(&rb[0]), rb1 = aldi(&rb[1]);

    // ---- stage tb into LDS + build per-block target-dst bitset (once) ----
    for (int i = tid; i < 1564; i += 256) tact[i] = 0ull;
    if (tid < B_ * K_) tbl_s[tid] = aldi(&tb[tid]);
    __syncthreads();
    if (tid < B_ * K_) {
        int b = tid / K_;
        int t = tbl_s[tid];
        atomicOr(&((unsigned*)tact)[t >> 4], 1u << (((t & 15) << 1) | b));
    }
    __syncthreads();

    // ---------- layers ----------
    for (int l = 0; l < L_; ++l) {
        const float* W    = A.layer_w + (size_t)l * 128 * 64;
        const float* bias = A.layer_b + l * 64;
        const float* gam  = A.ln_g + l * 64;
        const float* bet  = A.ln_b + l * 64;

        // ---- stage src-activity bitset to LDS (coherent u64 loads) ----
        {
            unsigned long long v0 = ald64(&gbs[tid]);
            unsigned long long v1 = ald64(&gbs[tid + 256]);
            unsigned long long v2 = ald64(&gbs[tid + 512]);
            unsigned long long v3 = ald64(&gbs[tid + 768]);
            unsigned long long v4 = ald64(&gbs[tid + 1024]);
            unsigned long long v5 = ald64(&gbs[tid + 1280]);
            unsigned long long v6 = (tid < 28) ? ald64(&gbs[1536 + tid]) : 0ull;
            bsll[tid] = v0; bsll[tid + 256] = v1; bsll[tid + 512] = v2;
            bsll[tid + 768] = v3; bsll[tid + 1024] = v4; bsll[tid + 1280] = v5;
            if (tid < 28) bsll[1536 + tid] = v6;
        }
        __syncthreads();

        // ---- scan: O(E) cached probe + ballot-compacted active-edge scatter ----
        // l==2: edge must ALSO have dst in the target set (score only reads
        // the 66 target rows, so layer-3 aggregation is only needed there),
        // and claims are skipped entirely (no worklist needed after L3) —
        // the inner loop has no dependent atomic returns.
        {
            const unsigned* bs = (const unsigned*)bsll;
            const unsigned* tw = (const unsigned*)tact;
            // NV4 % 64 == 0 and stride % 64 == 0 -> trip count wave-uniform.
            for (int i = gtid; i < NV4; i += FTHREADS) {
                int4 u = ((const int4*)A.ei)[i];        // ei read-only: plain cached
                int sv[4] = {u.x, u.y, u.z, u.w};
                int dv[4] = {0, 0, 0, 0};
                unsigned act = 0;
                #pragma unroll
                for (int k = 0; k < 4; ++k) {
                    int s = sv[k];
                    act |= ((bs[s >> 4] >> ((s & 15) << 1)) & 3u) << (k * 2);
                }
                if (l == 2) {                           // wave-uniform branch
                    int4 ud = ((const int4*)(A.ei + E_))[i];
                    dv[0] = ud.x; dv[1] = ud.y; dv[2] = ud.z; dv[3] = ud.w;
                    unsigned tm = 0;
                    #pragma unroll
                    for (int k = 0; k < 4; ++k) {
                        int d = dv[k];
                        tm |= ((tw[d >> 4] >> ((d & 15) << 1)) & 3u) << (k * 2);
                    }
                    act &= tm;
                }
                int ibase = i - lane;                   // wave-uniform int4 base
                #pragma unroll
                for (int k = 0; k < 4; ++k) {
                    #pragma unroll
                    for (int b = 0; b < B_; ++b) {
                        unsigned long long mask = __ballot((act >> (k * 2 + b)) & 1);
                        while (mask) {
                            int j = __builtin_ctzll(mask);
                            mask &= mask - 1;
                            int e  = (ibase + j) * 4 + k;
                            int si = __shfl(sv[k], j, 64);
                            int di = (l == 2) ? __shfl(dv[k], j, 64)
                                              : A.ei[E_ + e];     // lane-uniform
                            int ti = A.etype[e];
                            float v = aldf(&x[(b * N_ + si) * D_ + lane])
                                    * A.rel[(b * R_ + ti) * D_ + lane];
                            atomicAdd(&agg[(b * N_ + di) * D_ + lane], v);
                            if (lane == 0 && l < 2) {
                                int old = atomicOr(&flags[b * N_ + di], 4);
                                if (!(old & 4)) {
                                    int idx = atomicAdd(rowcnt, 1);
                                    if (idx < ROWCAP) asti(&rowlist[idx], b * N_ + di);
                                }
                            }
                        }
                    }
                }
            }
        }
        gridbar(bar, ++bark);

        if (l < 2) {
            // ---- update: [agg(+boundary), x] @ W + b -> LN -> relu -> x += ----
            if (tid == 0) cnt_s = min(aldi(rowcnt), ROWCAP);
            __syncthreads();
            const int cnt = cnt_s;
            for (int idx = gw; idx < cnt; idx += FTHREADS >> 6) {
                int row = aldi(&rowlist[idx]);
                int f = aldi(&flags[row]);
                int b = (row >= N_) ? 1 : 0;
                int node = row - b * N_;
                float a = aldf(&agg[row * D_ + lane]);
                if (node == (b ? hb1 : hb0))            // boundary (= query)
                    a += A.rel[(b * R_ + (b ? rb1 : rb0)) * D_ + lane];
                float xo = (f & 1) ? aldf(&x[row * D_ + lane]) : 0.0f;
                float y = bias[lane];
                #pragma unroll 8
                for (int i = 0; i < 64; ++i)
                    y += __shfl(a, i, 64) * W[i * 64 + lane];
                #pragma unroll 8
                for (int i = 0; i < 64; ++i)
                    y += __shfl(xo, i, 64) * W[(64 + i) * 64 + lane];
                float mu = wave_sum64(y) * (1.0f / 64.0f);
                float dlt = y - mu;
                float var = wave_sum64(dlt * dlt) * (1.0f / 64.0f);
                float upd = fmaxf(dlt * rsqrtf(var + 1e-5f) * gam[lane] + bet[lane], 0.0f);
                astf(&x[row * D_ + lane], upd + xo);
                astf(&agg[row * D_ + lane], 0.0f);      // ready for next layer
                if (lane == 0) {
                    asti(&flags[row], f | 1);           // x-active
                    atomicOr(&bitset[node >> 4], 1u << (((node & 15) << 1) | b));
                }
            }
            gridbar(bar, ++bark);
        } else {
            // ---- L3 update + score fused, targets only, no barrier after ----
            // Each of the 66 (b,k) pairs is handled by one wave, fully
            // in-register: x3 is never stored. Duplicate (b,t) pairs compute
            // identical values into distinct out[gw] — no dedupe, no races.
            if (gw < B_ * K_) {
                int b = gw / K_;
                int t = tbl_s[gw];
                int row = b * N_ + t;
                int f = aldi(&flags[row]);
                float a = aldf(&agg[row * D_ + lane]);
                if (t == (b ? hb1 : hb0))               // boundary (= query)
                    a += A.rel[(b * R_ + (b ? rb1 : rb0)) * D_ + lane];
                float xo = (f & 1) ? aldf(&x[row * D_ + lane]) : 0.0f;
                float y = bias[lane];
                #pragma unroll 8
                for (int i = 0; i < 64; ++i)
                    y += __shfl(a, i, 64) * W[i * 64 + lane];
                #pragma unroll 8
                for (int i = 0; i < 64; ++i)
                    y += __shfl(xo, i, 64) * W[(64 + i) * 64 + lane];
                float mu = wave_sum64(y) * (1.0f / 64.0f);
                float dlt = y - mu;
                float var = wave_sum64(dlt * dlt) * (1.0f / 64.0f);
                float upd = fmaxf(dlt * rsqrtf(var + 1e-5f) * gam[lane] + bet[lane], 0.0f);
                float res = upd + xo;                   // x3[row], in-register
                // inline final MLP score
                float q = A.rel[(b * R_ + (b ? rb1 : rb0)) * D_ + lane];
                float acc = A.mlp_b1[lane];
                #pragma unroll 8
                for (int i = 0; i < 64; ++i)
                    acc += __shfl(res, i, 64) * A.mlp_w1[i * 64 + lane];
                #pragma unroll 8
                for (int i = 0; i < 64; ++i)
                    acc += __shfl(q, i, 64) * A.mlp_w1[(64 + i) * 64 + lane];
                acc = fmaxf(acc, 0.0f);
                float s = wave_sum64(acc * A.mlp_w2[lane]);
                if (lane == 0) A.out[gw] = s + A.mlp_b2[0];
            }
        }
    }

    // Reset magic so a future run never sees stale MAGIC with un-zeroed
    // counters (hang hazard if a poison pass is ever skipped).
    if (blockIdx.x == 0 && tid == 0) ast64(ready, 0ull);
}

// =====================================================================
// Fallback path: proven R1 multi-kernel pipeline (launch-error only)
// =====================================================================
__global__ void init_kernel(const int* __restrict__ raw,
                            int* __restrict__ hb, int* __restrict__ rb,
                            int* __restrict__ tb,
                            float* __restrict__ x, int* __restrict__ flags,
                            unsigned* __restrict__ bitset,
                            int* __restrict__ rowlist, int* __restrict__ rowcnt,
                            const float* __restrict__ rel) {
    __shared__ int stride_s;
    __shared__ int hs[B_], rs[B_];
    if (threadIdx.x == 0) {
        int all_hi_zero = 1;
        for (int i = 0; i < 99; i++)
            if (raw[2 * i + 1] != 0) { all_hi_zero = 0; break; }
        stride_s = all_hi_zero ? 2 : 1;
    }
    __syncthreads();
    int st = stride_s;
    for (int i = threadIdx.x; i < B_ * K_; i += blockDim.x)
        tb[i] = raw[(i * 3 + 1) * st];
    if (threadIdx.x < B_) {
        int b = threadIdx.x;
        int h = raw[(b * K_ * 3 + 0) * st];
        int r = raw[(b * K_ * 3 + 2) * st];
        hb[b] = h; rb[b] = r; hs[b] = h; rs[b] = r;
    }
    __syncthreads();
    int b = threadIdx.x >> 6;
    int lane = threadIdx.x & 63;
    int node = hs[b];
    int row = b * N_ + node;
    x[row * D_ + lane] = rel[(b * R_ + rs[b]) * D_ + lane];
    if (lane == 0) {
        atomicOr(&flags[row], 1 | 4);
        atomicOr(&bitset[node >> 4], 1u << (((node & 15) << 1) | b));
        int idx = atomicAdd(rowcnt, 1);
        if (idx < ROWCAP) rowlist[idx] = row;
    }
}

__global__ void scatter_kernel(const float* __restrict__ x, float* __restrict__ agg,
                               const int* __restrict__ ei, const int* __restrict__ etype,
                               const float* __restrict__ rel,
                               int* __restrict__ flags,
                               const unsigned* __restrict__ bitset,
                               int* __restrict__ rowlist, int* __restrict__ rowcnt) {
    __shared__ uint4 bs4[782];
    unsigned* bs = (unsigned*)bs4;
    const uint4* g4 = (const uint4*)bitset;
    for (int i = threadIdx.x; i < 781; i += 256) bs4[i] = g4[i];
    if (threadIdx.x == 0) bs[3124] = bitset[3124];
    const int t = blockIdx.x * 256 + threadIdx.x;
    const int4* s4 = (const int4*)ei;
    int4 u0 = s4[t];
    int v4p1 = t + SCAT_THREADS;
    bool ok1 = v4p1 < NV4;
    int4 u1 = s4[ok1 ? v4p1 : t];
    __syncthreads();
    const int lane = threadIdx.x & 63;
    const int wv4 = blockIdx.x * 256 + (threadIdx.x & ~63);
    #pragma unroll
    for (int p = 0; p < 2; p++) {
        int4 u = p ? u1 : u0;
        bool ok = p ? ok1 : true;
        int sv[4] = {u.x, u.y, u.z, u.w};
        unsigned act = 0;
        if (ok) {
            #pragma unroll
            for (int k = 0; k < 4; k++) {
                int s = sv[k];
                act |= ((bs[s >> 4] >> ((s & 15) << 1)) & 3u) << (k * 2);
            }
        }
        #pragma unroll
        for (int k = 0; k < 4; k++) {
            #pragma unroll
            for (int b = 0; b < B_; b++) {
                unsigned long long mask = __ballot((act >> (k * 2 + b)) & 1);
                while (mask) {
                    int i = __builtin_ctzll(mask);
                    mask &= mask - 1;
                    int e = (wv4 + i + p * SCAT_THREADS) * 4 + k;
                    int si = __shfl(sv[k], i, 64);
                    int di = ei[E_ + e];
                    int ti = etype[e];
                    float v = x[(b * N_ + si) * D_ + lane] * rel[(b * R_ + ti) * D_ + lane];
                    atomicAdd(&agg[(b * N_ + di) * D_ + lane], v);
                    if (lane == 0) {
                        int old = atomicOr(&flags[b * N_ + di], 2 | 4);
                        if (!(old & 4)) {
                            int idx = atomicAdd(rowcnt, 1);
                            if (idx < ROWCAP) rowlist[idx] = b * N_ + di;
                        }
                    }
                }
            }
        }
    }
}

__global__ void update_kernel(float* __restrict__ x, float* __restrict__ agg,
                              int* __restrict__ flags, unsigned* __restrict__ bitset,
                              const int* __restrict__ rowlist,
                              const int* __restrict__ rowcnt,
                              const int* __restrict__ hb, const int* __restrict__ rb,
                              const float* __restrict__ rel,
                              const float* __restrict__ W,
                              const float* __restrict__ bias,
                              const float* __restrict__ g,
                              const float* __restrict__ be) {
    const int lane = threadIdx.x & 63;
    const int cnt = min(*rowcnt, ROWCAP);
    int idx = blockIdx.x * (blockDim.x >> 6) + (threadIdx.x >> 6);
    const int nw = gridDim.x * (blockDim.x >> 6);
    for (; idx < cnt; idx += nw) {
        int row = rowlist[idx];
        int f = flags[row];
        int b = (row >= N_) ? 1 : 0;
        int node = row - b * N_;
        float a = agg[row * D_ + lane];
        if (row == b * N_ + hb[b])
            a += rel[(b * R_ + rb[b]) * D_ + lane];
        float xo = (f & 1) ? x[row * D_ + lane] : 0.0f;
        float y = bias[lane];
        #pragma unroll 8
        for (int i = 0; i < 64; i++) {
            float av = __shfl(a, i, 64);
            y += av * W[i * 64 + lane];
        }
        #pragma unroll 8
        for (int i = 0; i < 64; i++) {
            float xv = __shfl(xo, i, 64);
            y += xv * W[(64 + i) * 64 + lane];
        }
        float mu = wave_sum64(y) * (1.0f / 64.0f);
        float dlt = y - mu;
        float var = wave_sum64(dlt * dlt) * (1.0f / 64.0f);
        float upd = dlt * rsqrtf(var + 1e-5f) * g[lane] + be[lane];
        upd = fmaxf(upd, 0.0f);
        x[row * D_ + lane] = upd + xo;
        agg[row * D_ + lane] = 0.0f;
        if (lane == 0) {
            flags[row] = (f | 1) & ~2;
            atomicOr(&bitset[node >> 4], 1u << (((node & 15) << 1) | b));
        }
    }
}

__global__ void score_kernel(const float* __restrict__ x, const int* __restrict__ flags,
                             const int* __restrict__ tb, const int* __restrict__ rb,
                             const float* __restrict__ rel,
                             const float* __restrict__ w1,
                             const float* __restrict__ b1,
                             const float* __restrict__ w2,
                             const float* __restrict__ b2,
                             float* __restrict__ out) {
    int idx = blockIdx.x;
    int lane = threadIdx.x;
    int b = idx / K_;
    int t  = tb[idx];
    int r0 = rb[b];
    int row = b * N_ + t;
    float q   = rel[(b * R_ + r0) * D_ + lane];
    float hid = (flags[row] & 1) ? x[row * D_ + lane] : 0.0f;
    float acc = b1[lane];
    #pragma unroll 8
    for (int i = 0; i < 64; i++) acc += __shfl(hid, i, 64) * w1[i * 64 + lane];
    #pragma unroll 8
    for (int i = 0; i < 64; i++) acc += __shfl(q, i, 64) * w1[(64 + i) * 64 + lane];
    acc = fmaxf(acc, 0.0f);
    float s = wave_sum64(acc * w2[lane]);
    if (lane == 0) out[idx] = s + b2[0];
}

extern "C" void kernel_launch(void* const* d_in, const int* in_sizes, int n_in,
                              void* d_out, int out_size, void* d_ws, size_t ws_size,
                              hipStream_t stream) {
    const float* rel     = (const float*)d_in[0];
    const float* layer_w = (const float*)d_in[1];
    const float* layer_b = (const float*)d_in[2];
    const float* ln_g    = (const float*)d_in[3];
    const float* ln_b    = (const float*)d_in[4];
    const float* mlp_w1  = (const float*)d_in[5];
    const float* mlp_b1  = (const float*)d_in[6];
    const float* mlp_w2  = (const float*)d_in[7];
    const float* mlp_b2  = (const float*)d_in[8];
    const int* batch_raw = (const int*)d_in[9];
    const int* ei    = (const int*)d_in[10];
    const int* etype = (const int*)d_in[11];
    (void)in_sizes; (void)n_in; (void)out_size; (void)ws_size;

    char* ws = (char*)d_ws;

    FusedArgs fa;
    fa.rel = rel; fa.layer_w = layer_w; fa.layer_b = layer_b;
    fa.ln_g = ln_g; fa.ln_b = ln_b;
    fa.mlp_w1 = mlp_w1; fa.mlp_b1 = mlp_b1; fa.mlp_w2 = mlp_w2; fa.mlp_b2 = mlp_b2;
    fa.raw = batch_raw; fa.ei = ei; fa.etype = etype;
    fa.ws = ws; fa.out = (float*)d_out;
    void* kargs[] = { (void*)&fa };

    hipError_t err = hipLaunchCooperativeKernel(fused_kernel, dim3(FGRID), dim3(256),
                                                kargs, 0, stream);
    if (err != hipSuccess) {
        (void)hipGetLastError();                // clear sticky error
        // ---------- Fallback: proven R1 multi-kernel path ----------
        float* x        = (float*)(ws);
        float* agg      = (float*)(ws + 25600000);
        int* flags      = (int*)  (ws + 51200000);
        int* rowlist    = (int*)  (ws + 51600000);
        unsigned* bitset= (unsigned*)(ws + 51987488);
        int* rowcnt     = (int*)  (ws + 52000000);
        int* hb         = (int*)  (ws + 52000008);
        int* rb         = (int*)  (ws + 52000016);
        int* tb         = (int*)  (ws + 52000024);

        hipMemsetAsync(ws + 25600000, 0, 26400288, stream);
        init_kernel<<<1, 128, 0, stream>>>(batch_raw, hb, rb, tb, x, flags, bitset,
                                           rowlist, rowcnt, rel);
        for (int l = 0; l < L_; l++) {
            scatter_kernel<<<SCAT_BLOCKS, 256, 0, stream>>>(x, agg, ei, etype, rel,
                                                            flags, bitset, rowlist, rowcnt);
            update_kernel<<<256, 256, 0, stream>>>(x, agg, flags, bitset,
                                                   rowlist, rowcnt, hb, rb, rel,
                                                   layer_w + (size_t)l * 128 * 64,
                                                   layer_b + l * 64,
                                                   ln_g + l * 64,
                                                   ln_b + l * 64);
        }
        score_kernel<<<B_ * K_, 64, 0, stream>>>(x, flags, tb, rb, rel, mlp_w1, mlp_b1,
                                                 mlp_w2, mlp_b2, (float*)d_out);
    }
}

// Round 9
// 172.034 us; speedup vs baseline: 1.8602x; 1.0582x over previous
//
#include <hip/hip_runtime.h>

// Problem constants (fixed by the harness / reference setup_inputs)
#define B_ 2
#define K_ 33
#define N_ 50000
#define E_ 800000
#define R_ 200
#define D_ 64
#define L_ 3

#define ROWCAP 95000      // rowlist entries (tail carved for tree-barrier state)
#define NV4 200000        // E/4 int4-groups
#define SCAT_BLOCKS 391   // fallback scan grid
#define SCAT_THREADS (SCAT_BLOCKS * 256)
#define FGRID 256         // fused grid: 1 block/CU, co-resident via cooperative launch
#define FTHREADS (FGRID * 256)
#define NGRP 16           // barrier tree: 16 groups x 16 blocks
#define GSZ  16
#define READY_MAGIC 0x5F0F00D5CAFEB007ull
#define ZCHUNK 12696      // ceil((3,200,000 agg + 50,000 flags u64) / 256)

#define SCOPE_AG __HIP_MEMORY_SCOPE_AGENT

// ---- relaxed agent-scope (cross-XCD coherent, no cache-wide fences) ----
// R4-R8 lessons: ockl grid.sync ~45us/barrier; flat fence-free ~6us; tree
// ~3us; body cost = SERIALIZED coherence round trips (R8's removal of
// ~19K dependent claim/update chains in L3: 210 -> 76us profiled).
// This round: (1) balance P0 zeroing (block0 was a 4x straggler on
// flags), (2) replace 1.2M same-line global bitset staging loads with
// LDS bitsets rebuilt from the rowlist frontier (~90K loads total).
__device__ inline float aldf(float* p)            { return __hip_atomic_load(p, __ATOMIC_RELAXED, SCOPE_AG); }
__device__ inline void  astf(float* p, float v)   { __hip_atomic_store(p, v, __ATOMIC_RELAXED, SCOPE_AG); }
__device__ inline int   aldi(int* p)              { return __hip_atomic_load(p, __ATOMIC_RELAXED, SCOPE_AG); }
__device__ inline void  asti(int* p, int v)       { __hip_atomic_store(p, v, __ATOMIC_RELAXED, SCOPE_AG); }
__device__ inline unsigned aldu(unsigned* p)      { return __hip_atomic_load(p, __ATOMIC_RELAXED, SCOPE_AG); }
__device__ inline void  astu(unsigned* p, unsigned v) { __hip_atomic_store(p, v, __ATOMIC_RELAXED, SCOPE_AG); }
__device__ inline unsigned long long ald64(unsigned long long* p) { return __hip_atomic_load(p, __ATOMIC_RELAXED, SCOPE_AG); }
__device__ inline void  ast64(unsigned long long* p, unsigned long long v) { __hip_atomic_store(p, v, __ATOMIC_RELAXED, SCOPE_AG); }

// Two-level tree barrier, monotonic epochs (no reset races). See R6.
__device__ inline void gridbar(unsigned* bar, unsigned epoch) {
    __syncthreads();    // per-wave vmcnt(0) drain before s_barrier = release
    if (threadIdx.x == 0) {
        const int g = (int)(blockIdx.x >> 4);
        unsigned* gcnt = bar + (1 + g) * 32;
        unsigned* ggo  = gcnt + 1;
        unsigned prev = __hip_atomic_fetch_add(gcnt, 1u, __ATOMIC_RELAXED, SCOPE_AG);
        if (prev == epoch * GSZ - 1) {              // last arriver in group
            unsigned r = __hip_atomic_fetch_add(bar, 1u, __ATOMIC_RELAXED, SCOPE_AG);
            if (r == epoch * NGRP - 1) {            // last group -> release everyone
                #pragma unroll
                for (int i = 0; i < NGRP; ++i)
                    astu(bar + (1 + i) * 32 + 1, epoch);
            }
        }
        while (aldu(ggo) < epoch) __builtin_amdgcn_s_sleep(1);
    }
    __syncthreads();
}

__device__ inline float wave_sum64(float v) {
    for (int m = 32; m; m >>= 1) v += __shfl_xor(v, m, 64);
    return v;
}

// flags bits: 1 = x-active, 4 = rowlist claim.
// Workspace layout (proven ws_size >= 52,000,288):
//   x       @ 0           25,600,000  (reads gated by flags bit0)
//   agg     @ 25,600,000  25,600,000  (eager-zeroed, balanced; update re-zeroes)
//   flags   @ 51,200,000     400,000  (zeroed, balanced)
//   rowlist @ 51,600,000     380,000  (ROWCAP entries)
//   bar     @ 51,980,032       2,176  (17 x 128 B tree-barrier lines)
//   ready   @ 51,987,480  (u64 magic)
//   rowcnt  @ 52,000,000  hb @ +8  rb @ +16  tb @ +24 (264 B)

struct FusedArgs {
    const float *rel, *layer_w, *layer_b, *ln_g, *ln_b;
    const float *mlp_w1, *mlp_b1, *mlp_w2, *mlp_b2;
    const int *raw, *ei, *etype;
    char* ws;
    float* out;
};

__global__ __launch_bounds__(256) void fused_kernel(FusedArgs A) {
    char* ws = A.ws;
    float*    x       = (float*)(ws);
    float*    agg     = (float*)(ws + 25600000);
    int*      flags   = (int*)(ws + 51200000);
    int*      rowlist = (int*)(ws + 51600000);
    unsigned* bar     = (unsigned*)(ws + 51980032);
    unsigned long long* ready = (unsigned long long*)(ws + 51987480);
    int*      rowcnt  = (int*)(ws + 52000000);
    int*      hb      = (int*)(ws + 52000008);
    int*      rb      = (int*)(ws + 52000016);
    int*      tb      = (int*)(ws + 52000024);
    unsigned long long* aggu = (unsigned long long*)agg;   // 3,200,000 u64
    unsigned long long* fzu  = (unsigned long long*)flags; // 50,000 u64

    const int tid  = threadIdx.x;
    const int lane = tid & 63;
    const int gtid = blockIdx.x * 256 + tid;
    const int gw   = gtid >> 6;                 // global wave id, 0..1023

    __shared__ unsigned long long bsll[1564];   // 12,512 B LDS src-activity bitset
    __shared__ unsigned long long tact[1564];   // 12,512 B target-dst bitset (L3 filter)
    __shared__ int tbl_s[B_ * K_];              // staged t-indices (66)
    __shared__ int nz_s, cnt_s, fc_s;

    // ---- barrier bootstrap over poisoned ws (block0 publishes magic) ----
    if (blockIdx.x == 0) {
        for (int i = tid; i < 17 * 32; i += 256) astu(&bar[i], 0u);
        __syncthreads();                        // drains all zero-stores
        if (tid == 0) ast64(ready, READY_MAGIC);
    } else if (tid == 0) {
        while (ald64(ready) != READY_MAGIC) __builtin_amdgcn_s_sleep(1);
    }

    // ---------- P0: BALANCED zero (agg+flags as one u64 span) ----------
    // 3,250,000 u64 total, ~12.7K per block (R8: block0 did 50K alone and
    // gated the first barrier). Block 0 additionally decodes batch and
    // writes x seed rows (x region is untouched by zeroing -> no race).
    // flags/rowlist seeding is deferred to the L1 scan phase (post-bar1,
    // when all flags-zero stores are globally visible).
    {
        int lo = blockIdx.x * ZCHUNK;
        int hi = lo + ZCHUNK; if (hi > 3250000) hi = 3250000;
        for (int i = lo + tid; i < hi; i += 256) {
            if (i < 3200000) ast64(&aggu[i], 0ull);
            else             ast64(&fzu[i - 3200000], 0ull);
        }
    }
    if (blockIdx.x == 0) {
        if (tid == 0) { asti(rowcnt, 0); nz_s = 0; }
        __syncthreads();
        // int64-vs-int32 batch detect: any hi-word nonzero -> int32 (stride 1)
        if (tid < 99 && A.raw[2 * tid + 1] != 0) atomicOr(&nz_s, 1);
        __syncthreads();
        const int st = nz_s ? 1 : 2;
        for (int i = tid; i < B_ * K_; i += 256) asti(&tb[i], A.raw[(i * 3 + 1) * st]);
        if (tid < B_) {
            asti(&hb[tid], A.raw[(tid * K_ * 3 + 0) * st]);
            asti(&rb[tid], A.raw[(tid * K_ * 3 + 2) * st]);
        }
        __syncthreads();
        if (tid < 128) {                        // x seed only (no flags yet)
            int b = tid >> 6;
            int h = A.raw[(b * K_ * 3 + 0) * st];
            int r = A.raw[(b * K_ * 3 + 2) * st];
            astf(&x[(b * N_ + h) * D_ + lane], A.rel[(b * R_ + r) * D_ + lane]);
        }
    }
    unsigned bark = 0;
    gridbar(bar, ++bark);

    // hb/rb constant after P0 — hoist coherent reads once.
    const int hb0 = aldi(&hb[0]), hb1 = aldi(&hb[1]);
    const int rb0 = aldi(&rb[0]), rb1 = aldi(&rb[1]);

    // ---- stage tb into LDS + build per-block target-dst bitset (once) ----
    for (int i = tid; i < 1564; i += 256) tact[i] = 0ull;
    if (tid < B_ * K_) tbl_s[tid] = aldi(&tb[tid]);
    __syncthreads();
    if (tid < B_ * K_) {
        int b = tid / K_;
        int t = tbl_s[tid];
        atomicOr(&((unsigned*)tact)[t >> 4], 1u << (((t & 15) << 1) | b));
    }
    __syncthreads();

    // ---------- layers ----------
    for (int l = 0; l < L_; ++l) {
        const float* W    = A.layer_w + (size_t)l * 128 * 64;
        const float* bias = A.layer_b + l * 64;
        const float* gam  = A.ln_g + l * 64;
        const float* bet  = A.ln_b + l * 64;

        // ---- build LDS src-activity bitset from the frontier ----
        // l==0: frontier = the 2 seed rows (from hb, no global reads).
        // l>=1: frontier = rowlist[0..rowcnt) — every entry is x-active
        // (update processed the full list last layer). u64-paired reads.
        for (int i = tid; i < 1564; i += 256) bsll[i] = 0ull;
        if (tid == 0 && l > 0) fc_s = min(aldi(rowcnt), ROWCAP);
        __syncthreads();
        {
            unsigned* bsw = (unsigned*)bsll;
            if (l == 0) {
                if (tid == 0) {                 // sequential: words may collide
                    bsw[hb0 >> 4] |= 1u << (((hb0 & 15) << 1) | 0);
                    bsw[hb1 >> 4] |= 1u << (((hb1 & 15) << 1) | 1);
                }
            } else {
                int pairs = (fc_s + 1) >> 1;
                for (int i = tid; i < pairs; i += 256) {
                    unsigned long long v = ald64((unsigned long long*)&rowlist[2 * i]);
                    int r0 = (int)(unsigned)v;
                    int c0 = (r0 >= N_) ? 1 : 0, n0 = r0 - c0 * N_;
                    atomicOr(&bsw[n0 >> 4], 1u << (((n0 & 15) << 1) | c0));
                    if (2 * i + 1 < fc_s) {
                        int r1 = (int)(v >> 32);
                        int c1 = (r1 >= N_) ? 1 : 0, n1 = r1 - c1 * N_;
                        atomicOr(&bsw[n1 >> 4], 1u << (((n1 & 15) << 1) | c1));
                    }
                }
            }
        }
        __syncthreads();
        // Deferred flags/rowlist seeding (idempotent vs concurrent scan
        // claims: atomicOr serializes, exactly one appender sees !old&4).
        if (l == 0 && blockIdx.x == 0 && tid < B_) {
            int row = tid * N_ + (tid ? hb1 : hb0);
            int old = atomicOr(&flags[row], 1 | 4);
            if (!(old & 4)) {
                int idx = atomicAdd(rowcnt, 1);
                if (idx < ROWCAP) asti(&rowlist[idx], row);
            }
        }

        // ---- scan: O(E) cached probe + ballot-compacted active-edge scatter ----
        // l==2: dst must be in the target set (score reads only the 66
        // target rows) and claims are skipped — no dependent atomic returns.
        {
            const unsigned* bs = (const unsigned*)bsll;
            const unsigned* tw = (const unsigned*)tact;
            // NV4 % 64 == 0 and stride % 64 == 0 -> trip count wave-uniform.
            for (int i = gtid; i < NV4; i += FTHREADS) {
                int4 u = ((const int4*)A.ei)[i];        // ei read-only: plain cached
                int sv[4] = {u.x, u.y, u.z, u.w};
                int dv[4] = {0, 0, 0, 0};
                unsigned act = 0;
                #pragma unroll
                for (int k = 0; k < 4; ++k) {
                    int s = sv[k];
                    act |= ((bs[s >> 4] >> ((s & 15) << 1)) & 3u) << (k * 2);
                }
                if (l == 2) {                           // wave-uniform branch
                    int4 ud = ((const int4*)(A.ei + E_))[i];
                    dv[0] = ud.x; dv[1] = ud.y; dv[2] = ud.z; dv[3] = ud.w;
                    unsigned tm = 0;
                    #pragma unroll
                    for (int k = 0; k < 4; ++k) {
                        int d = dv[k];
                        tm |= ((tw[d >> 4] >> ((d & 15) << 1)) & 3u) << (k * 2);
                    }
                    act &= tm;
                }
                int ibase = i - lane;                   // wave-uniform int4 base
                #pragma unroll
                for (int k = 0; k < 4; ++k) {
                    #pragma unroll
                    for (int b = 0; b < B_; ++b) {
                        unsigned long long mask = __ballot((act >> (k * 2 + b)) & 1);
                        while (mask) {
                            int j = __builtin_ctzll(mask);
                            mask &= mask - 1;
                            int e  = (ibase + j) * 4 + k;
                            int si = __shfl(sv[k], j, 64);
                            int di = (l == 2) ? __shfl(dv[k], j, 64)
                                              : A.ei[E_ + e];     // lane-uniform
                            int ti = A.etype[e];
                            float v = aldf(&x[(b * N_ + si) * D_ + lane])
                                    * A.rel[(b * R_ + ti) * D_ + lane];
                            atomicAdd(&agg[(b * N_ + di) * D_ + lane], v);
                            if (lane == 0 && l < 2) {
                                int old = atomicOr(&flags[b * N_ + di], 4);
                                if (!(old & 4)) {
                                    int idx = atomicAdd(rowcnt, 1);
                                    if (idx < ROWCAP) asti(&rowlist[idx], b * N_ + di);
                                }
                            }
                        }
                    }
                }
            }
        }
        gridbar(bar, ++bark);

        if (l < 2) {
            // ---- update: [agg(+boundary), x] @ W + b -> LN -> relu -> x += ----
            if (tid == 0) cnt_s = min(aldi(rowcnt), ROWCAP);
            __syncthreads();
            const int cnt = cnt_s;
            for (int idx = gw; idx < cnt; idx += FTHREADS >> 6) {
                int row = aldi(&rowlist[idx]);
                int f = aldi(&flags[row]);
                int b = (row >= N_) ? 1 : 0;
                int node = row - b * N_;
                float a = aldf(&agg[row * D_ + lane]);
                if (node == (b ? hb1 : hb0))            // boundary (= query)
                    a += A.rel[(b * R_ + (b ? rb1 : rb0)) * D_ + lane];
                float xo = (f & 1) ? aldf(&x[row * D_ + lane]) : 0.0f;
                float y = bias[lane];
                #pragma unroll 8
                for (int i = 0; i < 64; ++i)
                    y += __shfl(a, i, 64) * W[i * 64 + lane];
                #pragma unroll 8
                for (int i = 0; i < 64; ++i)
                    y += __shfl(xo, i, 64) * W[(64 + i) * 64 + lane];
                float mu = wave_sum64(y) * (1.0f / 64.0f);
                float dlt = y - mu;
                float var = wave_sum64(dlt * dlt) * (1.0f / 64.0f);
                float upd = fmaxf(dlt * rsqrtf(var + 1e-5f) * gam[lane] + bet[lane], 0.0f);
                astf(&x[row * D_ + lane], upd + xo);
                astf(&agg[row * D_ + lane], 0.0f);      // ready for next layer
                if (lane == 0)
                    asti(&flags[row], f | 1);           // x-active
            }
            gridbar(bar, ++bark);
        } else {
            // ---- L3 update + score fused, targets only, no barrier after ----
            // One wave per (b,k) pair, fully in-register; duplicates compute
            // identical values into distinct out[gw] — no dedupe, no races.
            if (gw < B_ * K_) {
                int b = gw / K_;
                int t = tbl_s[gw];
                int row = b * N_ + t;
                int f = aldi(&flags[row]);
                float a = aldf(&agg[row * D_ + lane]);
                if (t == (b ? hb1 : hb0))               // boundary (= query)
                    a += A.rel[(b * R_ + (b ? rb1 : rb0)) * D_ + lane];
                float xo = (f & 1) ? aldf(&x[row * D_ + lane]) : 0.0f;
                float y = bias[lane];
                #pragma unroll 8
                for (int i = 0; i < 64; ++i)
                    y += __shfl(a, i, 64) * W[i * 64 + lane];
                #pragma unroll 8
                for (int i = 0; i < 64; ++i)
                    y += __shfl(xo, i, 64) * W[(64 + i) * 64 + lane];
                float mu = wave_sum64(y) * (1.0f / 64.0f);
                float dlt = y - mu;
                float var = wave_sum64(dlt * dlt) * (1.0f / 64.0f);
                float upd = fmaxf(dlt * rsqrtf(var + 1e-5f) * gam[lane] + bet[lane], 0.0f);
                float res = upd + xo;                   // x3[row], in-register
                // inline final MLP score
                float q = A.rel[(b * R_ + (b ? rb1 : rb0)) * D_ + lane];
                float acc = A.mlp_b1[lane];
                #pragma unroll 8
                for (int i = 0; i < 64; ++i)
                    acc += __shfl(res, i, 64) * A.mlp_w1[i * 64 + lane];
                #pragma unroll 8
                for (int i = 0; i < 64; ++i)
                    acc += __shfl(q, i, 64) * A.mlp_w1[(64 + i) * 64 + lane];
                acc = fmaxf(acc, 0.0f);
                float s = wave_sum64(acc * A.mlp_w2[lane]);
                if (lane == 0) A.out[gw] = s + A.mlp_b2[0];
            }
        }
    }

    // Reset magic so a future run never sees stale MAGIC with un-zeroed
    // counters (hang hazard if a poison pass is ever skipped).
    if (blockIdx.x == 0 && tid == 0) ast64(ready, 0ull);
}

// =====================================================================
// Fallback path: proven R1 multi-kernel pipeline (launch-error only)
// =====================================================================
__global__ void init_kernel(const int* __restrict__ raw,
                            int* __restrict__ hb, int* __restrict__ rb,
                            int* __restrict__ tb,
                            float* __restrict__ x, int* __restrict__ flags,
                            unsigned* __restrict__ bitset,
                            int* __restrict__ rowlist, int* __restrict__ rowcnt,
                            const float* __restrict__ rel) {
    __shared__ int stride_s;
    __shared__ int hs[B_], rs[B_];
    if (threadIdx.x == 0) {
        int all_hi_zero = 1;
        for (int i = 0; i < 99; i++)
            if (raw[2 * i + 1] != 0) { all_hi_zero = 0; break; }
        stride_s = all_hi_zero ? 2 : 1;
    }
    __syncthreads();
    int st = stride_s;
    for (int i = threadIdx.x; i < B_ * K_; i += blockDim.x)
        tb[i] = raw[(i * 3 + 1) * st];
    if (threadIdx.x < B_) {
        int b = threadIdx.x;
        int h = raw[(b * K_ * 3 + 0) * st];
        int r = raw[(b * K_ * 3 + 2) * st];
        hb[b] = h; rb[b] = r; hs[b] = h; rs[b] = r;
    }
    __syncthreads();
    int b = threadIdx.x >> 6;
    int lane = threadIdx.x & 63;
    int node = hs[b];
    int row = b * N_ + node;
    x[row * D_ + lane] = rel[(b * R_ + rs[b]) * D_ + lane];
    if (lane == 0) {
        atomicOr(&flags[row], 1 | 4);
        atomicOr(&bitset[node >> 4], 1u << (((node & 15) << 1) | b));
        int idx = atomicAdd(rowcnt, 1);
        if (idx < ROWCAP) rowlist[idx] = row;
    }
}

__global__ void scatter_kernel(const float* __restrict__ x, float* __restrict__ agg,
                               const int* __restrict__ ei, const int* __restrict__ etype,
                               const float* __restrict__ rel,
                               int* __restrict__ flags,
                               const unsigned* __restrict__ bitset,
                               int* __restrict__ rowlist, int* __restrict__ rowcnt) {
    __shared__ uint4 bs4[782];
    unsigned* bs = (unsigned*)bs4;
    const uint4* g4 = (const uint4*)bitset;
    for (int i = threadIdx.x; i < 781; i += 256) bs4[i] = g4[i];
    if (threadIdx.x == 0) bs[3124] = bitset[3124];
    const int t = blockIdx.x * 256 + threadIdx.x;
    const int4* s4 = (const int4*)ei;
    int4 u0 = s4[t];
    int v4p1 = t + SCAT_THREADS;
    bool ok1 = v4p1 < NV4;
    int4 u1 = s4[ok1 ? v4p1 : t];
    __syncthreads();
    const int lane = threadIdx.x & 63;
    const int wv4 = blockIdx.x * 256 + (threadIdx.x & ~63);
    #pragma unroll
    for (int p = 0; p < 2; p++) {
        int4 u = p ? u1 : u0;
        bool ok = p ? ok1 : true;
        int sv[4] = {u.x, u.y, u.z, u.w};
        unsigned act = 0;
        if (ok) {
            #pragma unroll
            for (int k = 0; k < 4; k++) {
                int s = sv[k];
                act |= ((bs[s >> 4] >> ((s & 15) << 1)) & 3u) << (k * 2);
            }
        }
        #pragma unroll
        for (int k = 0; k < 4; k++) {
            #pragma unroll
            for (int b = 0; b < B_; b++) {
                unsigned long long mask = __ballot((act >> (k * 2 + b)) & 1);
                while (mask) {
                    int i = __builtin_ctzll(mask);
                    mask &= mask - 1;
                    int e = (wv4 + i + p * SCAT_THREADS) * 4 + k;
                    int si = __shfl(sv[k], i, 64);
                    int di = ei[E_ + e];
                    int ti = etype[e];
                    float v = x[(b * N_ + si) * D_ + lane] * rel[(b * R_ + ti) * D_ + lane];
                    atomicAdd(&agg[(b * N_ + di) * D_ + lane], v);
                    if (lane == 0) {
                        int old = atomicOr(&flags[b * N_ + di], 2 | 4);
                        if (!(old & 4)) {
                            int idx = atomicAdd(rowcnt, 1);
                            if (idx < ROWCAP) rowlist[idx] = b * N_ + di;
                        }
                    }
                }
            }
        }
    }
}

__global__ void update_kernel(float* __restrict__ x, float* __restrict__ agg,
                              int* __restrict__ flags, unsigned* __restrict__ bitset,
                              const int* __restrict__ rowlist,
                              const int* __restrict__ rowcnt,
                              const int* __restrict__ hb, const int* __restrict__ rb,
                              const float* __restrict__ rel,
                              const float* __restrict__ W,
                              const float* __restrict__ bias,
                              const float* __restrict__ g,
                              const float* __restrict__ be) {
    const int lane = threadIdx.x & 63;
    const int cnt = min(*rowcnt, ROWCAP);
    int idx = blockIdx.x * (blockDim.x >> 6) + (threadIdx.x >> 6);
    const int nw = gridDim.x * (blockDim.x >> 6);
    for (; idx < cnt; idx += nw) {
        int row = rowlist[idx];
        int f = flags[row];
        int b = (row >= N_) ? 1 : 0;
        int node = row - b * N_;
        float a = agg[row * D_ + lane];
        if (row == b * N_ + hb[b])
            a += rel[(b * R_ + rb[b]) * D_ + lane];
        float xo = (f & 1) ? x[row * D_ + lane] : 0.0f;
        float y = bias[lane];
        #pragma unroll 8
        for (int i = 0; i < 64; i++) {
            float av = __shfl(a, i, 64);
            y += av * W[i * 64 + lane];
        }
        #pragma unroll 8
        for (int i = 0; i < 64; i++) {
            float xv = __shfl(xo, i, 64);
            y += xv * W[(64 + i) * 64 + lane];
        }
        float mu = wave_sum64(y) * (1.0f / 64.0f);
        float dlt = y - mu;
        float var = wave_sum64(dlt * dlt) * (1.0f / 64.0f);
        float upd = dlt * rsqrtf(var + 1e-5f) * g[lane] + be[lane];
        upd = fmaxf(upd, 0.0f);
        x[row * D_ + lane] = upd + xo;
        agg[row * D_ + lane] = 0.0f;
        if (lane == 0) {
            flags[row] = (f | 1) & ~2;
            atomicOr(&bitset[node >> 4], 1u << (((node & 15) << 1) | b));
        }
    }
}

__global__ void score_kernel(const float* __restrict__ x, const int* __restrict__ flags,
                             const int* __restrict__ tb, const int* __restrict__ rb,
                             const float* __restrict__ rel,
                             const float* __restrict__ w1,
                             const float* __restrict__ b1,
                             const float* __restrict__ w2,
                             const float* __restrict__ b2,
                             float* __restrict__ out) {
    int idx = blockIdx.x;
    int lane = threadIdx.x;
    int b = idx / K_;
    int t  = tb[idx];
    int r0 = rb[b];
    int row = b * N_ + t;
    float q   = rel[(b * R_ + r0) * D_ + lane];
    float hid = (flags[row] & 1) ? x[row * D_ + lane] : 0.0f;
    float acc = b1[lane];
    #pragma unroll 8
    for (int i = 0; i < 64; i++) acc += __shfl(hid, i, 64) * w1[i * 64 + lane];
    #pragma unroll 8
    for (int i = 0; i < 64; i++) acc += __shfl(q, i, 64) * w1[(64 + i) * 64 + lane];
    acc = fmaxf(acc, 0.0f);
    float s = wave_sum64(acc * w2[lane]);
    if (lane == 0) out[idx] = s + b2[0];
}

extern "C" void kernel_launch(void* const* d_in, const int* in_sizes, int n_in,
                              void* d_out, int out_size, void* d_ws, size_t ws_size,
                              hipStream_t stream) {
    const float* rel     = (const float*)d_in[0];
    const float* layer_w = (const float*)d_in[1];
    const float* layer_b = (const float*)d_in[2];
    const float* ln_g    = (const float*)d_in[3];
    const float* ln_b    = (const float*)d_in[4];
    const float* mlp_w1  = (const float*)d_in[5];
    const float* mlp_b1  = (const float*)d_in[6];
    const float* mlp_w2  = (const float*)d_in[7];
    const float* mlp_b2  = (const float*)d_in[8];
    const int* batch_raw = (const int*)d_in[9];
    const int* ei    = (const int*)d_in[10];
    const int* etype = (const int*)d_in[11];
    (void)in_sizes; (void)n_in; (void)out_size; (void)ws_size;

    char* ws = (char*)d_ws;

    FusedArgs fa;
    fa.rel = rel; fa.layer_w = layer_w; fa.layer_b = layer_b;
    fa.ln_g = ln_g; fa.ln_b = ln_b;
    fa.mlp_w1 = mlp_w1; fa.mlp_b1 = mlp_b1; fa.mlp_w2 = mlp_w2; fa.mlp_b2 = mlp_b2;
    fa.raw = batch_raw; fa.ei = ei; fa.etype = etype;
    fa.ws = ws; fa.out = (float*)d_out;
    void* kargs[] = { (void*)&fa };

    hipError_t err = hipLaunchCooperativeKernel(fused_kernel, dim3(FGRID), dim3(256),
                                                kargs, 0, stream);
    if (err != hipSuccess) {
        (void)hipGetLastError();                // clear sticky error
        // ---------- Fallback: proven R1 multi-kernel path ----------
        float* x        = (float*)(ws);
        float* agg      = (float*)(ws + 25600000);
        int* flags      = (int*)  (ws + 51200000);
        int* rowlist    = (int*)  (ws + 51600000);
        unsigned* bitset= (unsigned*)(ws + 51987488);
        int* rowcnt     = (int*)  (ws + 52000000);
        int* hb         = (int*)  (ws + 52000008);
        int* rb         = (int*)  (ws + 52000016);
        int* tb         = (int*)  (ws + 52000024);

        hipMemsetAsync(ws + 25600000, 0, 26400288, stream);
        init_kernel<<<1, 128, 0, stream>>>(batch_raw, hb, rb, tb, x, flags, bitset,
                                           rowlist, rowcnt, rel);
        for (int l = 0; l < L_; l++) {
            scatter_kernel<<<SCAT_BLOCKS, 256, 0, stream>>>(x, agg, ei, etype, rel,
                                                            flags, bitset, rowlist, rowcnt);
            update_kernel<<<256, 256, 0, stream>>>(x, agg, flags, bitset,
                                                   rowlist, rowcnt, hb, rb, rel,
                                                   layer_w + (size_t)l * 128 * 64,
                                                   layer_b + l * 64,
                                                   ln_g + l * 64,
                                                   ln_b + l * 64);
        }
        score_kernel<<<B_ * K_, 64, 0, stream>>>(x, flags, tb, rb, rel, mlp_w1, mlp_b1,
                                                 mlp_w2, mlp_b2, (float*)d_out);
    }
}